// Round 2
// baseline (283.366 us; speedup 1.0000x reference)
//
#include <hip/hip_runtime.h>

// x[B=16,C=64,H=224,W=224] fp32, dct_bases[M=16,16,16] fp32 -> out[B,M,H,W] fp32.
#define B_   16
#define C_   64
#define H_   224
#define W_   224
#define M_   16
#define PH   16
#define PW   16
#define HP   14                    // H/PH
#define WP   14                    // W/PW
#define PLANE (H_ * W_)            // 50176 floats per (b,c) plane
#define PLANE4 (PLANE / 4)         // 12544 float4 per plane
#define BAND  (PH * W_)            // 3584 floats per (b,hp) row-band
#define BAND4 (BAND / 4)           // 896 float4 per band
#define LSTRIDE 228                // LDS row stride: 228%32=4 -> only 2-way bank alias (free)

typedef float f4 __attribute__((ext_vector_type(4)));

// ---------------- K1: channel mean, fully-coalesced streaming read ----------------
// grid: (PLANE4/256, B_); thread handles one float4 of mean[b], loops 64 channels.
// x is streamed exactly once with zero reuse -> non-temporal loads keep it out of
// L2/LLC so the 3.2 MB mean stays resident for K2's 16x re-read.
__global__ __launch_bounds__(256)
void k1_mean(const float* __restrict__ x, float* __restrict__ mean) {
    const int f4i = blockIdx.x * 256 + threadIdx.x;  // 0..PLANE4-1
    const int b   = blockIdx.y;
    const f4* p = (const f4*)x + (size_t)b * C_ * PLANE4 + f4i;
    f4 acc = {0.f, 0.f, 0.f, 0.f};
#pragma unroll 16
    for (int c = 0; c < C_; ++c) {
        f4 v = __builtin_nontemporal_load(&p[(size_t)c * PLANE4]);
        acc += v;
    }
    const float inv = 1.f / (float)C_;
    acc *= inv;
    ((f4*)mean)[(size_t)b * PLANE4 + f4i] = acc;   // regular store: mean IS reused
}

// ---------------- K2: fused DCT-project + broadcast-write ----------------
// grid: (M_, HP, B_) = 3584 blocks, 256 threads.
// Block (m, hp, b): loads the (b,hp) mean band (16 rows x 224) into LDS,
// computes coeff[wp] for its basis m across wp=0..13, then writes its
// contiguous output band out[b][m][hp*16:+16][:] with 1 KB/wave stores.
__global__ __launch_bounds__(256)
void k2_dct_write(const float* __restrict__ mean, const float* __restrict__ bases,
                  float* __restrict__ out) {
    const int m  = blockIdx.x;
    const int hp = blockIdx.y;
    const int b  = blockIdx.z;
    const int t  = threadIdx.x;

    __shared__ float band[PH * LSTRIDE];   // 16 x 228 = 14.6 KB
    __shared__ float cf[WP];               // 14 coefficients

    // Phase 1: coalesced load of the mean band into LDS (L2/LLC-resident).
    const f4* src = (const f4*)(mean + (size_t)b * PLANE + (size_t)hp * BAND);
    for (int j = t; j < BAND4; j += 256) {
        const int row  = j / (W_ / 4);     // 0..15
        const int col4 = j % (W_ / 4);     // 0..55
        *(f4*)&band[row * LSTRIDE + col4 * 4] = src[j];
    }
    __syncthreads();

    // Phase 2: 14 dot products (one per wp) for basis m.
    // thread t < 224: wp = t>>4, s = t&15; partial over row s's 16 cols.
    if (t < WP * 16) {
        const int wp = t >> 4;
        const int s  = t & 15;
        const float* brow = bases + m * (PH * PW) + s * PW;
        float partial = 0.f;
#pragma unroll
        for (int k = 0; k < 16; ++k)
            partial += band[s * LSTRIDE + wp * PW + k] * brow[k];
        partial += __shfl_xor(partial, 1);
        partial += __shfl_xor(partial, 2);
        partial += __shfl_xor(partial, 4);
        partial += __shfl_xor(partial, 8);
        if (s == 0) cf[wp] = partial;
    }
    __syncthreads();

    // Phase 3: contiguous broadcast-write of the output band (896 float4).
    // out is written once, never read -> non-temporal stores.
    f4* dst = (f4*)(out + ((size_t)b * M_ + m) * PLANE + (size_t)hp * BAND);
#pragma unroll
    for (int j4 = 0; j4 < BAND4; j4 += 256) {
        const int j    = j4 + t;
        const int col4 = j % (W_ / 4);     // 0..55
        if (j < BAND4) {
            const float c = cf[col4 >> 2]; // wp = (col4*4)/16
            f4 v = {c, c, c, c};
            __builtin_nontemporal_store(v, &dst[j]);
        }
    }
}

extern "C" void kernel_launch(void* const* d_in, const int* in_sizes, int n_in,
                              void* d_out, int out_size, void* d_ws, size_t ws_size,
                              hipStream_t stream) {
    const float* x     = (const float*)d_in[0];
    const float* bases = (const float*)d_in[1];
    float* out         = (float*)d_out;

    float* mean = (float*)d_ws;            // B_*PLANE floats = 3.2 MB

    dim3 g1(PLANE4 / 256, B_);             // 49 x 16 = 784 blocks
    k1_mean<<<g1, 256, 0, stream>>>(x, mean);

    dim3 g2(M_, HP, B_);                   // 16 x 14 x 16 = 3584 blocks
    k2_dct_write<<<g2, 256, 0, stream>>>(mean, bases, out);
}

// Round 3
// 282.631 us; speedup vs baseline: 1.0026x; 1.0026x over previous
//
#include <hip/hip_runtime.h>

// x[B=16,C=64,H=224,W=224] fp32, dct_bases[M=16,16,16] fp32 -> out[B,M,H,W] fp32.
// Single fused kernel: per (column-half, hp, b) block, stream x over channels to a
// mean band in LDS, project onto 16 DCT bases, broadcast-write 16 output bands.
#define B_   16
#define C_   64
#define H_   224
#define W_   224
#define M_   16
#define PH   16
#define PW   16
#define HP   14                    // H/PH
#define WP   14                    // W/PW
#define PLANE  (H_ * W_)           // 50176 floats per (b,c) plane
#define PLANE4 (PLANE / 4)         // 12544 float4 per plane
#define W4     (W_ / 4)            // 56 f4 per row
#define NSPLIT 2                   // column splits per band
#define CW     (W_ / NSPLIT)       // 112 cols per block
#define CW4    (CW / 4)            // 28 f4 per row-segment
#define WPB    (WP / NSPLIT)       // 7 patch-cols per block
#define SLOTS  (PH * CW4)          // 448 f4 slots per band-slab
#define LSTW   116                 // LDS band row stride (floats): 112 + 4 pad, 16B-aligned

typedef float f4 __attribute__((ext_vector_type(4)));

__global__ __launch_bounds__(256)
void k_fused(const float* __restrict__ x, const float* __restrict__ bases,
             float* __restrict__ out) {
    const int cb = blockIdx.x;          // 0..1   column half
    const int hp = blockIdx.y;          // 0..13  patch row
    const int b  = blockIdx.z;          // 0..15  batch
    const int t  = threadIdx.x;

    __shared__ float band[PH][LSTW];    // mean band: 16 x 116 floats = 7.4 KB
    __shared__ float bs[M_ * PH * PW];  // DCT bases: 16 KB
    __shared__ float cf[M_][WPB];       // 16 x 7 coefficients

    // Stage bases into LDS (1024 f4, 4 per thread) -- overlaps with x loads below.
    {
        const f4* bsrc = (const f4*)bases;
        f4* bdst = (f4*)bs;
#pragma unroll
        for (int i = 0; i < 4; ++i)
            bdst[t + i * 256] = bsrc[t + i * 256];
    }

    // Phase 1: channel-mean of the (b, hp, cb) slab into LDS.
    // 448 f4 slots; thread t owns slots t and t+256 (t+256 valid only for t<192,
    // which is wave-uniform: waves 0-2 take the 2-slot path, wave 3 the 1-slot path).
    {
        const int j0 = t;
        const int j1 = t + 256;
        const int r0 = j0 / CW4, c0 = j0 % CW4;
        const int r1 = j1 / CW4, c1 = j1 % CW4;
        const f4* p0 = (const f4*)x + (size_t)b * C_ * PLANE4
                     + (hp * PH + r0) * W4 + cb * CW4 + c0;
        const f4* p1 = (const f4*)x + (size_t)b * C_ * PLANE4
                     + (hp * PH + r1) * W4 + cb * CW4 + c1;
        f4 a0 = {0.f, 0.f, 0.f, 0.f};
        f4 a1 = {0.f, 0.f, 0.f, 0.f};
        if (j1 < SLOTS) {
#pragma unroll 8
            for (int c = 0; c < C_; ++c) {
                a0 += __builtin_nontemporal_load(&p0[(size_t)c * PLANE4]);
                a1 += __builtin_nontemporal_load(&p1[(size_t)c * PLANE4]);
            }
        } else {
#pragma unroll 8
            for (int c = 0; c < C_; ++c)
                a0 += __builtin_nontemporal_load(&p0[(size_t)c * PLANE4]);
        }
        const float inv = 1.f / (float)C_;
        a0 *= inv; a1 *= inv;
        *(f4*)&band[r0][c0 * 4] = a0;
        if (j1 < SLOTS) *(f4*)&band[r1][c1 * 4] = a1;
    }
    __syncthreads();

    // Phase 2: 112 dot products (16 m x 7 wp), vectorized f4 LDS reads.
    if (t < M_ * WPB) {
        const int m  = t / WPB;
        const int wp = t % WPB;
        const float* bm = &bs[m * PH * PW];
        f4 sv = {0.f, 0.f, 0.f, 0.f};
#pragma unroll
        for (int r = 0; r < PH; ++r) {
#pragma unroll
            for (int q = 0; q < 4; ++q) {
                f4 bv = *(const f4*)&band[r][wp * PW + q * 4];
                f4 mv = *(const f4*)&bm[r * PW + q * 4];
                sv += bv * mv;
            }
        }
        cf[m][wp] = sv.x + sv.y + sv.z + sv.w;
    }
    __syncthreads();

    // Phase 3: broadcast-write 16 output bands (16 m x 448 f4 = 7168 f4, NT stores).
    f4* dst = (f4*)out + (size_t)(b * M_) * PLANE4 + (hp * PH) * W4 + cb * CW4;
#pragma unroll
    for (int it = 0; it < (M_ * SLOTS) / 256; ++it) {   // 28 iterations
        const int idx = it * 256 + t;
        const int m   = idx / SLOTS;
        const int j   = idx % SLOTS;
        const int r   = j / CW4, c4 = j % CW4;
        const float v = cf[m][c4 >> 2];
        f4 vv = {v, v, v, v};
        __builtin_nontemporal_store(vv, &dst[(size_t)m * PLANE4 + r * W4 + c4]);
    }
}

extern "C" void kernel_launch(void* const* d_in, const int* in_sizes, int n_in,
                              void* d_out, int out_size, void* d_ws, size_t ws_size,
                              hipStream_t stream) {
    const float* x     = (const float*)d_in[0];
    const float* bases = (const float*)d_in[1];
    float* out         = (float*)d_out;

    dim3 g(NSPLIT, HP, B_);                // 2 x 14 x 16 = 448 blocks
    k_fused<<<g, 256, 0, stream>>>(x, bases, out);
}

// Round 4
// 280.575 us; speedup vs baseline: 1.0100x; 1.0073x over previous
//
#include <hip/hip_runtime.h>

// x[B=16,C=64,H=224,W=224] fp32, dct_bases[M=16,16,16] fp32 -> out[B,M,H,W] fp32.
// Fused kernel, occupancy-raised: grid (7 col-slices x 14 hp x 16 b) = 1568 blocks,
// 256 threads. Per block: 2-way channel-split mean of a 16x32 slab into LDS,
// reduce, project onto 16 bases (2 patch-cols), broadcast-write 16 output slabs.
#define B_   16
#define C_   64
#define H_   224
#define W_   224
#define M_   16
#define PH   16
#define PW   16
#define HP   14                    // H/PH
#define WP   14                    // W/PW
#define PLANE  (H_ * W_)           // 50176 floats per (b,c) plane
#define PLANE4 (PLANE / 4)         // 12544 float4 per plane
#define W4     (W_ / 4)            // 56 f4 per row
#define NSPLIT 7                   // column slices per band (must divide WP=14)
#define CW     (W_ / NSPLIT)       // 32 cols per block
#define CW4    (CW / 4)            // 8 f4 per row-segment (128 B)
#define WPB    (WP / NSPLIT)       // 2 patch-cols per block
#define SLOTS  (PH * CW4)          // 128 f4 slots per slab
#define LSTW   36                  // LDS row stride (floats): 32+4 pad, 16B-aligned

typedef float f4 __attribute__((ext_vector_type(4)));

__global__ __launch_bounds__(256)
void k_fused(const float* __restrict__ x, const float* __restrict__ bases,
             float* __restrict__ out) {
    const int cb = blockIdx.x;          // 0..6   column slice
    const int hp = blockIdx.y;          // 0..13  patch row
    const int b  = blockIdx.z;          // 0..15  batch
    const int t  = threadIdx.x;

    __shared__ float band2[2][PH][LSTW];   // per-channel-half sums: 4.6 KB
    __shared__ float bs[M_ * PH * PW];     // DCT bases: 16 KB
    __shared__ float cf[M_][WPB];          // 16 x 2 coefficients

    // Stage bases into LDS (1024 f4, 4 per thread) -- overlaps with x loads.
    {
        const f4* bsrc = (const f4*)bases;
        f4* bdst = (f4*)bs;
#pragma unroll
        for (int i = 0; i < 4; ++i)
            bdst[t + i * 256] = bsrc[t + i * 256];
    }

    // Phase 1: channel-split partial mean. Thread t: slot j = t&127 (one f4 of the
    // 16x32 slab), channel half = t>>7 (32 channels each). All 256 threads load.
    {
        const int j     = t & 127;
        const int chalf = t >> 7;
        const int r  = j >> 3;          // 0..15
        const int c4 = j & 7;           // 0..7
        const f4* p = (const f4*)x + (size_t)b * C_ * PLANE4
                    + (size_t)(chalf * 32) * PLANE4
                    + (hp * PH + r) * W4 + cb * CW4 + c4;
        f4 a = {0.f, 0.f, 0.f, 0.f};
#pragma unroll 8
        for (int i = 0; i < 32; ++i)
            a += __builtin_nontemporal_load(&p[(size_t)i * PLANE4]);
        *(f4*)&band2[chalf][r][c4 * 4] = a;
    }
    __syncthreads();

    // Phase 2: 32 dot products (16 m x 2 wp), 8 threads each (2 rows/thread),
    // channel-half reduction folded in. 32 groups x 8 lanes = 256 threads.
    {
        const int g   = t >> 3;         // 0..31: (m, wpl)
        const int m   = g >> 1;
        const int wpl = g & 1;
        const int rp  = t & 7;          // row pair index
        const float* bm = &bs[m * PH * PW];
        f4 sv = {0.f, 0.f, 0.f, 0.f};
#pragma unroll
        for (int rr = 0; rr < 2; ++rr) {
            const int r = rp * 2 + rr;
#pragma unroll
            for (int q = 0; q < 4; ++q) {
                f4 bv = *(const f4*)&band2[0][r][wpl * PW + q * 4]
                      + *(const f4*)&band2[1][r][wpl * PW + q * 4];
                f4 mv = *(const f4*)&bm[r * PW + q * 4];
                sv += bv * mv;
            }
        }
        float s = sv.x + sv.y + sv.z + sv.w;
        s += __shfl_xor(s, 1);
        s += __shfl_xor(s, 2);
        s += __shfl_xor(s, 4);
        if (rp == 0) cf[m][wpl] = s * (1.f / (float)C_);
    }
    __syncthreads();

    // Phase 3: broadcast-write 16 output slabs (16 m x 128 f4 = 2048 f4, NT).
    f4* dst = (f4*)out + (size_t)b * M_ * PLANE4 + (hp * PH) * W4 + cb * CW4;
#pragma unroll
    for (int it = 0; it < (M_ * SLOTS) / 256; ++it) {   // 8 iterations
        const int idx = it * 256 + t;
        const int m   = idx >> 7;       // 0..15
        const int j   = idx & 127;
        const int r   = j >> 3;         // 0..15
        const int c4  = j & 7;          // 0..7
        const float v = cf[m][c4 >> 2];
        f4 vv = {v, v, v, v};
        __builtin_nontemporal_store(vv, &dst[(size_t)m * PLANE4 + r * W4 + c4]);
    }
}

extern "C" void kernel_launch(void* const* d_in, const int* in_sizes, int n_in,
                              void* d_out, int out_size, void* d_ws, size_t ws_size,
                              hipStream_t stream) {
    const float* x     = (const float*)d_in[0];
    const float* bases = (const float*)d_in[1];
    float* out         = (float*)d_out;

    dim3 g(NSPLIT, HP, B_);                // 7 x 14 x 16 = 1568 blocks
    k_fused<<<g, 256, 0, stream>>>(x, bases, out);
}